// Round 5
// baseline (182.863 us; speedup 1.0000x reference)
//
#include <hip/hip_runtime.h>
#include <hip/hip_cooperative_groups.h>
#include <cmath>

namespace cg = cooperative_groups;

#define NAT  2048
#define NP   65536
#define CAP  64        // per-atom pair bucket capacity
#define SCAP 8192      // flat staged-pair capacity (expected ~3400)
#define SSTR 120       // floats per staged record: rad[40] | g[70] | sp[4] | pad

// ---- angular monomial exponent tables --------------------------------------
__constant__ int GLX[70] = {0,
  0,0,0,1,
  0,0,0,0,0,0,1,1,1,2,
  0,0,0,0,0,0,0,0,0,0,1,1,1,1,1,1,2,2,2,3,
  0,0,0,0,0,0,0,0,0,0,0,0,0,0,0,1,1,1,1,1,1,1,1,1,1,2,2,2,2,2,2,3,3,3,4};
__constant__ int GLY[70] = {0,
  0,0,1,0,
  0,0,0,1,1,2,0,0,1,0,
  0,0,0,0,1,1,1,2,2,3,0,0,0,1,1,2,0,0,1,0,
  0,0,0,0,0,1,1,1,1,2,2,2,3,3,4,0,0,0,0,1,1,1,2,2,3,0,0,0,1,1,2,0,0,1,0};
__constant__ int GLZ[70] = {0,
  0,1,0,0,
  0,1,2,0,1,0,0,1,0,0,
  0,1,2,3,0,1,2,0,1,0,0,1,2,0,1,0,0,1,0,0,
  0,1,2,3,4,0,1,2,3,0,1,2,0,1,0,0,1,2,3,0,1,2,0,1,0,0,1,2,0,1,0,0,1,0,0};
// c = z!/((z-n)! lx! ly! lz!), per-zeta blocks
__constant__ float C_ALL[69] = {
  1,1,1,1,
  1,2,1,2,2,1,2,2,2,1,
  1,3,3,1,3,6,3,3,3,1,3,6,3,6,6,3,3,3,3,1,
  1,4,6,4,1,4,12,12,4,6,12,6,4,4,1,4,12,12,4,12,24,12,12,12,4,6,12,6,12,12,6,4,4,4,1};
// c * (-1)^n
__constant__ float CS_ALL[69] = {
  1,-1,-1,-1,
  1,-2,1,-2,2,1,-2,2,2,1,
  1,-3,3,-1,-3,6,-3,3,-3,-1,-3,6,-3,6,-6,-3,3,-3,-3,-1,
  1,-4,6,-4,1,-4,12,-12,4,6,-12,6,-4,4,1,-4,12,-12,4,12,-24,12,-12,12,4,6,-12,6,-12,12,6,-4,4,4,1};
__constant__ int LTAB[4]    = {4,10,20,35};
__constant__ int CUMTAB[4]  = {0,4,14,34};
__constant__ int BASETAB[4] = {32,160,480,1120};

__device__ __forceinline__ float silu_f(float x){ return x / (1.0f + expf(-x)); }

// One cooperative kernel: 256 blocks x 512 threads.
// P0 zero -> P1 pair filter/bucket -> P2 wave-per-pair staging ->
// P3 per-block 8-atom gather + feature (LDS Fs) -> P4 MLP -> P5 reduce.
__global__ __launch_bounds__(512) void k_all(
    const float* __restrict__ pos,  const float* __restrict__ cell,
    const float* __restrict__ oneh,
    const float* __restrict__ sw1,  const float* __restrict__ sb1,
    const float* __restrict__ sw2,  const float* __restrict__ sb2,
    const float* __restrict__ rw1,  const float* __restrict__ rb1,
    const float* __restrict__ rw2,  const float* __restrict__ rb2,
    const float* __restrict__ aw1,  const float* __restrict__ ab1,
    const float* __restrict__ aw2,  const float* __restrict__ ab2,
    const float* __restrict__ aw3,  const float* __restrict__ ab3,
    const int* __restrict__ i1,     const int* __restrict__ i2,
    const int* __restrict__ sv,
    int* cursor, int* nflat, int* order, int* slot2flat, int* flat,
    float* staged, float* partials, float* out)
{
  cg::grid_group grid = cg::this_grid();
  const int tid = threadIdx.x, blk = blockIdx.x;
  const int gid = blk*512 + tid;
  __shared__ __align__(16) char smem[58368];

  // ---- P0: zero counters ----
  if (gid < NAT) cursor[gid] = 0;
  if (gid == 0)  *nflat = 0;
  grid.sync();

  // ---- P1: pair cutoff test -> per-atom bucket + flat list ----
  if (gid < NP){
    const int p = gid;
    const int a = i1[p], b = i2[p];
    const float s0=(float)sv[p*3+0], s1=(float)sv[p*3+1], s2=(float)sv[p*3+2];
    const float rx = pos[b*3+0]-pos[a*3+0] + s0*cell[0]+s1*cell[3]+s2*cell[6];
    const float ry = pos[b*3+1]-pos[a*3+1] + s0*cell[1]+s1*cell[4]+s2*cell[7];
    const float rz = pos[b*3+2]-pos[a*3+2] + s0*cell[2]+s1*cell[5]+s2*cell[8];
    const float r = sqrtf(rx*rx+ry*ry+rz*rz + 1e-12f);
    if (r < 5.0f){
      int s = atomicAdd(&cursor[a], 1);
      if (s < CAP){
        int fs = atomicAdd(nflat, 1);
        order[a*CAP + s] = p;
        if (fs < SCAP){ slot2flat[a*CAP + s] = fs; flat[fs] = p; }
        else          { slot2flat[a*CAP + s] = -1; }
      }
    }
  }
  grid.sync();

  // ---- P2: one wave per contributing pair: staged record ----
  {
    int ntot = *nflat; if (ntot > SCAP) ntot = SCAP;
    const int lane = tid & 63;
    const int w0 = blk*8 + (tid >> 6);        // 2048 waves grid-wide
    for (int w = w0; w < ntot; w += 2048){
      const int pid = flat[w];
      const int a = i1[pid], b = i2[pid];
      const float s0=(float)sv[pid*3+0], s1=(float)sv[pid*3+1], s2=(float)sv[pid*3+2];
      const float rx = pos[b*3+0]-pos[a*3+0] + s0*cell[0]+s1*cell[3]+s2*cell[6];
      const float ry = pos[b*3+1]-pos[a*3+1] + s0*cell[1]+s1*cell[4]+s2*cell[7];
      const float rz = pos[b*3+2]-pos[a*3+2] + s0*cell[2]+s1*cell[5]+s2*cell[8];
      const float r  = sqrtf(rx*rx+ry*ry+rz*rz + 1e-12f);
      const float inv= 1.0f/r;
      const float ux=rx*inv, uy=ry*inv, uz=rz*inv;
      const float fc = 0.5f*(cosf(0.6283185307179586f*r)+1.0f);  // pi/RC

      float basis[8];
#pragma unroll
      for (int kk=0;kk<8;kk++){
        float d = r - (float)kk*(5.0f/7.0f);                     // linspace(0,5,8)
        basis[kk] = expf(-d*d*1.28f)*fc;                         // 1/(2*0.625^2)
      }
      // radial layer 1: lane o owns h_o
      float h = rb1[lane];
#pragma unroll
      for (int kk=0;kk<8;kk++) h += basis[kk]*rw1[kk*64+lane];
      h = silu_f(h);
      // radial layer 2: lanes 0..39 own rad_n via in-wave broadcast
      const int ln = (lane < 40) ? lane : 0;
      float racc = rb2[ln];
#pragma unroll
      for (int o=0;o<64;o++){
        float hb = __shfl(h, o);
        racc += hb * rw2[o*40 + ln];
      }
      float* dst = staged + (size_t)w*SSTR;
      if (lane < 40) dst[lane] = racc*fc;
      // angular monomials
      {
        int ex=GLX[lane], ey=GLY[lane], ez=GLZ[lane];
        float g=1.f;
        for (int q=0;q<ex;q++) g*=ux;
        for (int q=0;q<ey;q++) g*=uy;
        for (int q=0;q<ez;q++) g*=uz;
        dst[40+lane]=g;
      }
      if (lane < 6){
        int l2 = 64+lane;
        int ex=GLX[l2], ey=GLY[l2], ez=GLZ[l2];
        float g=1.f;
        for (int q=0;q<ex;q++) g*=ux;
        for (int q=0;q<ey;q++) g*=uy;
        for (int q=0;q<ez;q++) g*=uz;
        dst[104+lane]=g;
      }
      // species embedding of neighbor b, in-wave (one-hot -> row select)
      {
        const float o1=oneh[b*4+1], o2=oneh[b*4+2], o3=oneh[b*4+3];
        const int spec = (int)(o1 + 2.0f*o2 + 3.0f*o3 + 0.5f);
        float hh = silu_f(sb1[lane] + sw1[spec*64+lane]);
        const float4 w2 = ((const float4*)sw2)[lane];
        float q0=hh*w2.x, q1=hh*w2.y, q2=hh*w2.z, q3=hh*w2.w;
#pragma unroll
        for (int off=32; off>0; off>>=1){
          q0 += __shfl_xor(q0, off); q1 += __shfl_xor(q1, off);
          q2 += __shfl_xor(q2, off); q3 += __shfl_xor(q3, off);
        }
        if (lane < 4){
          float v = (lane==0) ? q0+sb2[0] : (lane==1) ? q1+sb2[1]
                  : (lane==2) ? q2+sb2[2] : q3+sb2[3];
          dst[110+lane] = v;
        }
      }
    }
  }
  grid.sync();

  // ---- P3: per-block 8 atoms, gather-accumulate + feature into LDS Fs ----
  float* G    = (float*)(smem);          // 2240 f  [0,8960)
  float* sbuf = (float*)(smem+8960);     // 8*120 f [8960,12800)
  int*   opid = (int*)  (smem+12800);    // 64 i
  int*   pslot= (int*)  (smem+13056);    // 64 i
  int*   sflb = (int*)  (smem+13312);    // 8 i
  float* Fs   = (float*)(smem+16384);    // 8*288 f [16384,25600)

  int ridx[5], gidx[5], eidx[5];
#pragma unroll
  for (int k=0;k<5;k++){
    int a = tid + (k<<9);
    int ri=0, gi=0, ei=0;
    if (a < 32){ ri = a>>2; gi = 0; ei = a&3; }
    else if (a < 2240){
      int b = a-32; int lb, nl, l, n;
      if (b < 128)      { lb=b;      ei=lb&3; nl=lb>>2; l=nl%4;  n=nl/4;  ri=8 +n; gi=1 +l; }
      else if (b < 448) { lb=b-128;  ei=lb&3; nl=lb>>2; l=nl%10; n=nl/10; ri=16+n; gi=5 +l; }
      else if (b < 1088){ lb=b-448;  ei=lb&3; nl=lb>>2; l=nl%20; n=nl/20; ri=24+n; gi=15+l; }
      else              { lb=b-1088; ei=lb&3; nl=lb>>2; l=nl%35; n=nl/35; ri=32+n; gi=35+l; }
    }
    ridx[k]=ri; gidx[k]=gi; eidx[k]=ei;
  }

  for (int aa=0; aa<8; aa++){
    const int atom = blk*8 + aa;
    int cnt = cursor[atom]; if (cnt > CAP) cnt = CAP;
    if (tid < CAP) opid[tid] = (tid < cnt) ? order[atom*CAP + tid] : 0x7fffffff;
    __syncthreads();
    if (tid < cnt){                      // rank-sort by pair id -> deterministic
      int my = opid[tid]; int rk = 0;
      for (int j=0;j<cnt;j++) rk += (opid[j] < my);
      pslot[rk] = tid;
    }
    float acc[5] = {0.f,0.f,0.f,0.f,0.f};
    __syncthreads();

    for (int c0=0; c0<cnt; c0+=8){
      const int nc = (cnt-c0 < 8) ? (cnt-c0) : 8;
      if (tid < nc) sflb[tid] = slot2flat[atom*CAP + pslot[c0+tid]];
      __syncthreads();
      for (int idx=tid; idx<nc*SSTR; idx+=512){
        int jj = idx/SSTR, i = idx - jj*SSTR;
        int fsl = sflb[jj];
        sbuf[idx] = (fsl >= 0) ? staged[(size_t)fsl*SSTR + i] : 0.f;
      }
      __syncthreads();
      for (int jj=0;jj<nc;jj++){
        const float* sd = sbuf + jj*SSTR;
#pragma unroll
        for (int k=0;k<5;k++)
          acc[k] += sd[ridx[k]] * sd[40+gidx[k]] * sd[110+eidx[k]];
      }
      __syncthreads();
    }

#pragma unroll
    for (int k=0;k<5;k++){
      int a = tid + (k<<9);
      if (a < 2240) G[a] = acc[k];
    }
    __syncthreads();

    float* Fo = Fs + aa*288;
    if (tid < 32) Fo[tid] = G[tid];
    if (tid < 128){
      const int zi = tid>>5, n=(tid>>2)&7, e=tid&3;
      const int L = LTAB[zi], cb = CUMTAB[zi], bs = BASETAB[zi];
      float ap=0.f, am=0.f;
      for (int l=0;l<L;l++){
        float v  = G[bs + ((n*L + l)<<2) + e];
        float v2 = v*v;
        ap += C_ALL [cb+l]*v2;
        am += CS_ALL[cb+l]*v2;
      }
      Fo[32 + (zi<<6)      + (n<<2) + e] = ap;
      Fo[32 + (zi<<6) + 32 + (n<<2) + e] = am;
    }
    __syncthreads();
  }

  // ---- P4: MLP for this block's 8 atoms (Fs already in LDS) ----
  float* P1 = (float*)(smem+25600);      // 2*8*256 f [25600,41984)
  float* Hs = (float*)(smem);            // 8*256 f   [0,8192)      (G dead)
  float* P2 = (float*)(smem+41984);      // 4*8*128 f [41984,58368)
  float* Ps = (float*)(smem+8192);       // 8*128 f   [8192,12288)
  float* es = (float*)(smem+12288);      // 8 f

  {
    const int o = tid & 255, half = tid >> 8;
    const int i0 = half*144;
    float p1[8];
#pragma unroll
    for (int a=0;a<8;a++) p1[a]=0.f;
    for (int i=i0;i<i0+144;i++){
      float w = aw1[i*256 + o];
#pragma unroll
      for (int a=0;a<8;a++) p1[a] += Fs[a*288+i]*w;
    }
#pragma unroll
    for (int a=0;a<8;a++) P1[half*2048 + a*256 + o] = p1[a];
  }
  __syncthreads();
  {
    const int o = tid & 255, half = tid >> 8;
    if (half == 0){
#pragma unroll
      for (int a=0;a<8;a++)
        Hs[a*256+o] = silu_f(ab1[o] + P1[a*256+o] + P1[2048 + a*256+o]);
    }
  }
  __syncthreads();
  {
    const int o = tid & 127, q = tid >> 7;
    const int i0 = q*64;
    float p2[8];
#pragma unroll
    for (int a=0;a<8;a++) p2[a]=0.f;
    for (int i=i0;i<i0+64;i++){
      float w = aw2[i*128 + o];
#pragma unroll
      for (int a=0;a<8;a++) p2[a] += Hs[a*256+i]*w;
    }
#pragma unroll
    for (int a=0;a<8;a++) P2[q*1024 + a*128 + o] = p2[a];
  }
  __syncthreads();
#pragma unroll
  for (int rep=0; rep<2; rep++){
    int idx = tid + rep*512;
    int a = idx >> 7, o = idx & 127;
    float h2 = ab2[o] + P2[a*128+o] + P2[1024+a*128+o]
             + P2[2048+a*128+o] + P2[3072+a*128+o];
    Ps[a*128+o] = silu_f(h2)*aw3[o];
  }
  __syncthreads();
  {
    const int wv = tid >> 6, lane = tid & 63;
    float s = Ps[wv*128+lane] + Ps[wv*128+64+lane];
    for (int off=32; off>0; off>>=1) s += __shfl_xor(s, off);
    if (lane == 0) es[wv] = s;
  }
  __syncthreads();
  if (tid == 0){
    partials[blk] = es[0]+es[1]+es[2]+es[3]+es[4]+es[5]+es[6]+es[7] + 8.0f*ab3[0];
  }
  grid.sync();

  // ---- P5: block 0 reduces 256 partials ----
  if (blk == 0){
    float* red = (float*)smem;
    red[tid] = (tid < 256) ? partials[tid] : 0.f;
    __syncthreads();
    for (int off=256; off>0; off>>=1){
      if (tid < off) red[tid] += red[tid+off];
      __syncthreads();
    }
    if (tid == 0) out[0] = red[0];
  }
}

extern "C" void kernel_launch(void* const* d_in, const int* in_sizes, int n_in,
                              void* d_out, int out_size, void* d_ws, size_t ws_size,
                              hipStream_t stream) {
  const float* pos  = (const float*)d_in[0];
  const float* cell = (const float*)d_in[1];
  const float* oneh = (const float*)d_in[2];
  const float* sw1  = (const float*)d_in[3];
  const float* sb1  = (const float*)d_in[4];
  const float* sw2  = (const float*)d_in[5];
  const float* sb2  = (const float*)d_in[6];
  const float* rw1  = (const float*)d_in[7];
  const float* rb1  = (const float*)d_in[8];
  const float* rw2  = (const float*)d_in[9];
  const float* rb2  = (const float*)d_in[10];
  const float* aw1  = (const float*)d_in[11];
  const float* ab1  = (const float*)d_in[12];
  const float* aw2  = (const float*)d_in[13];
  const float* ab2  = (const float*)d_in[14];
  const float* aw3  = (const float*)d_in[15];
  const float* ab3  = (const float*)d_in[16];
  const int*   i1   = (const int*)d_in[17];
  const int*   i2   = (const int*)d_in[18];
  const int*   sv   = (const int*)d_in[19];

  char* ws = (char*)d_ws;
  int*   cursor    = (int*)  (ws + 0);         // 8192 B
  int*   nflat     = (int*)  (ws + 8192);      // 256 B
  int*   order     = (int*)  (ws + 8448);      // NAT*CAP*4 = 524288 B
  int*   slot2flat = (int*)  (ws + 532736);    // 524288 B
  int*   flat      = (int*)  (ws + 1057024);   // SCAP*4 = 32768 B
  float* staged    = (float*)(ws + 1089792);   // SCAP*SSTR*4 = 3932160 B
  float* partials  = (float*)(ws + 5021952);   // 1024 B -> total ~5.02 MB
  float* outf      = (float*)d_out;

  void* args[] = {
    (void*)&pos, (void*)&cell, (void*)&oneh,
    (void*)&sw1, (void*)&sb1, (void*)&sw2, (void*)&sb2,
    (void*)&rw1, (void*)&rb1, (void*)&rw2, (void*)&rb2,
    (void*)&aw1, (void*)&ab1, (void*)&aw2, (void*)&ab2,
    (void*)&aw3, (void*)&ab3,
    (void*)&i1, (void*)&i2, (void*)&sv,
    (void*)&cursor, (void*)&nflat, (void*)&order, (void*)&slot2flat,
    (void*)&flat, (void*)&staged, (void*)&partials, (void*)&outf
  };
  hipLaunchCooperativeKernel((void*)k_all, dim3(256), dim3(512), args, 0, stream);
}

// Round 6
// 109.083 us; speedup vs baseline: 1.6764x; 1.6764x over previous
//
#include <hip/hip_runtime.h>
#include <cmath>

#define NAT  2048
#define NP   65536
#define CAP  64        // per-atom pair bucket capacity
#define SCAP 8192      // compact staged-pair capacity (expected ~3400)
#define SSTR 120       // floats per staged record: rad[40] | g[70] | sp[4] | pad

// ---- angular monomial exponent tables --------------------------------------
__constant__ int GLX[70] = {0,
  0,0,0,1,
  0,0,0,0,0,0,1,1,1,2,
  0,0,0,0,0,0,0,0,0,0,1,1,1,1,1,1,2,2,2,3,
  0,0,0,0,0,0,0,0,0,0,0,0,0,0,0,1,1,1,1,1,1,1,1,1,1,2,2,2,2,2,2,3,3,3,4};
__constant__ int GLY[70] = {0,
  0,0,1,0,
  0,0,0,1,1,2,0,0,1,0,
  0,0,0,0,1,1,1,2,2,3,0,0,0,1,1,2,0,0,1,0,
  0,0,0,0,0,1,1,1,1,2,2,2,3,3,4,0,0,0,0,1,1,1,2,2,3,0,0,0,1,1,2,0,0,1,0};
__constant__ int GLZ[70] = {0,
  0,1,0,0,
  0,1,2,0,1,0,0,1,0,0,
  0,1,2,3,0,1,2,0,1,0,0,1,2,0,1,0,0,1,0,0,
  0,1,2,3,4,0,1,2,3,0,1,2,0,1,0,0,1,2,3,0,1,2,0,1,0,0,1,2,0,1,0,0,1,0,0};
// c = z!/((z-n)! lx! ly! lz!), per-zeta blocks (verified 4+10+20+35 = 69)
__constant__ float C_ALL[69] = {
  1,1,1,1,
  1,2,1,2,2,1,2,2,2,1,
  1,3,3,1,3,6,3,3,3,1,3,6,3,6,6,3,3,3,3,1,
  1,4,6,4,1,4,12,12,4,6,12,6,4,4,1,4,12,12,4,12,24,12,12,12,4,6,12,6,12,12,6,4,4,4,1};
// c * (-1)^n  (verified 35 tokens in z4 block)
__constant__ float CS_ALL[69] = {
  1,-1,-1,-1,
  1,-2,1,-2,2,1,-2,2,2,1,
  1,-3,3,-1,-3,6,-3,3,-3,-1,-3,6,-3,6,-6,-3,3,-3,-3,-1,
  1,-4,6,-4,1,-4,12,-12,4,6,-12,6,-4,4,1,-4,12,-12,4,12,-24,12,-12,12,4,6,-12,6,-12,12,6,-4,4,4,1};
__constant__ int LTAB[4]    = {4,10,20,35};
__constant__ int CUMTAB[4]  = {0,4,14,34};
__constant__ int BASETAB[4] = {32,160,480,1120};

__device__ __forceinline__ float silu_f(float x){ return x / (1.0f + expf(-x)); }

// ---- kernel A: fused pair filter + wave-wide staging -----------------------
// 256 blocks x 256 thr = 1024 waves; wave g owns pairs [g*64, g*64+64).
// Ballot-compact survivors, then stage each survivor with the whole wave.
__global__ __launch_bounds__(256) void k_pairstage(
    const float* __restrict__ pos, const float* __restrict__ cell,
    const float* __restrict__ oneh,
    const int* __restrict__ i1, const int* __restrict__ i2,
    const int* __restrict__ sv,
    const float* __restrict__ sw1, const float* __restrict__ sb1,
    const float* __restrict__ sw2, const float* __restrict__ sb2,
    const float* __restrict__ rw1, const float* __restrict__ rb1,
    const float* __restrict__ rw2, const float* __restrict__ rb2,
    int* __restrict__ cursor, int* __restrict__ nflat,
    int* __restrict__ ord_pid, int* __restrict__ ord_flat,
    float* __restrict__ staged)
{
  __shared__ float sembs[4][4];
  const int tid = threadIdx.x, lane = tid & 63, wid = tid >> 6;

  // per-block species embedding table: wave w computes species w
  {
    float h = silu_f(sb1[lane] + sw1[wid*64 + lane]);
    const float4 w2 = ((const float4*)sw2)[lane];
    float q0=h*w2.x, q1=h*w2.y, q2=h*w2.z, q3=h*w2.w;
#pragma unroll
    for (int off=32; off>0; off>>=1){
      q0 += __shfl_xor(q0, off); q1 += __shfl_xor(q1, off);
      q2 += __shfl_xor(q2, off); q3 += __shfl_xor(q3, off);
    }
    if (lane < 4){
      float v = (lane==0) ? q0+sb2[0] : (lane==1) ? q1+sb2[1]
              : (lane==2) ? q2+sb2[2] : q3+sb2[3];
      sembs[wid][lane] = v;
    }
  }
  __syncthreads();

  // each lane evaluates one pair
  const int p = (blockIdx.x*4 + wid)*64 + lane;
  const int a = i1[p], b = i2[p];
  const float s0=(float)sv[p*3+0], s1=(float)sv[p*3+1], s2=(float)sv[p*3+2];
  const float rx = pos[b*3+0]-pos[a*3+0] + s0*cell[0]+s1*cell[3]+s2*cell[6];
  const float ry = pos[b*3+1]-pos[a*3+1] + s0*cell[1]+s1*cell[4]+s2*cell[7];
  const float rz = pos[b*3+2]-pos[a*3+2] + s0*cell[2]+s1*cell[5]+s2*cell[8];
  const float r  = sqrtf(rx*rx+ry*ry+rz*rz + 1e-12f);
  const bool ok  = (r < 5.0f);
  const float inv= 1.0f/r;
  const float ux=rx*inv, uy=ry*inv, uz=rz*inv;
  const float fcl= 0.5f*(cosf(0.6283185307179586f*r)+1.0f);     // pi/RC

  const unsigned long long mask = __ballot(ok);
  const int nsurv = __popcll(mask);
  if (nsurv == 0) return;

  int base = 0;
  if (lane == 0) base = atomicAdd(nflat, nsurv);
  base = __shfl(base, 0);
  const int rank = __popcll(mask & ((1ull<<lane)-1ull));
  const int fs = base + rank;                                   // compact slot
  if (ok){
    int s = atomicAdd(&cursor[a], 1);
    if (s < CAP){
      ord_pid [a*CAP + s] = p;
      ord_flat[a*CAP + s] = fs;
    }
  }

  // stage each survivor wave-wide
  unsigned long long m = mask;
  while (m){
    const int src = __ffsll((long long)m) - 1; m &= m-1;
    const float sux=__shfl(ux,src), suy=__shfl(uy,src), suz=__shfl(uz,src);
    const float sr =__shfl(r ,src), sfc=__shfl(fcl,src);
    const int   sb_=__shfl(b ,src), sfs=__shfl(fs ,src);
    if (sfs >= SCAP) continue;
    float* dst = staged + (size_t)sfs*SSTR;

    float basis[8];
#pragma unroll
    for (int kk=0;kk<8;kk++){
      float d = sr - (float)kk*(5.0f/7.0f);                     // linspace(0,5,8)
      basis[kk] = expf(-d*d*1.28f)*sfc;                         // 1/(2*0.625^2)
    }
    // radial layer 1: lane o owns h_o
    float h = rb1[lane];
#pragma unroll
    for (int kk=0;kk<8;kk++) h += basis[kk]*rw1[kk*64+lane];
    h = silu_f(h);
    // radial layer 2: lanes 0..39 own rad_n via in-wave broadcast
    const int ln = (lane < 40) ? lane : 0;
    float racc = rb2[ln];
#pragma unroll
    for (int o=0;o<64;o++){
      float hb = __shfl(h, o);
      racc += hb * rw2[o*40 + ln];
    }
    if (lane < 40) dst[lane] = racc*sfc;
    // angular monomials: lane l -> g_l (l<64), lanes 0..5 -> g_{64..69}
    {
      int ex=GLX[lane], ey=GLY[lane], ez=GLZ[lane];
      float g=1.f;
      for (int q=0;q<ex;q++) g*=sux;
      for (int q=0;q<ey;q++) g*=suy;
      for (int q=0;q<ez;q++) g*=suz;
      dst[40+lane]=g;
    }
    if (lane < 6){
      int l2 = 64+lane;
      int ex=GLX[l2], ey=GLY[l2], ez=GLZ[l2];
      float g=1.f;
      for (int q=0;q<ex;q++) g*=sux;
      for (int q=0;q<ey;q++) g*=suy;
      for (int q=0;q<ez;q++) g*=suz;
      dst[104+lane]=g;
    }
    // species embedding of neighbor (from per-block table)
    const float o1=oneh[sb_*4+1], o2=oneh[sb_*4+2], o3=oneh[sb_*4+3];
    const int spec = (int)(o1 + 2.0f*o2 + 3.0f*o3 + 0.5f);
    if (lane < 4) dst[110+lane] = sembs[spec][lane];
  }
}

// ---- kernel B: per-atom gather-accumulate + feature build ------------------
// Block per atom, 256 threads; thread t owns accumulator slots t+256k, k<9.
__global__ __launch_bounds__(256) void k_feat(
    const int* __restrict__ cursor,
    const int* __restrict__ ord_pid, const int* __restrict__ ord_flat,
    const float* __restrict__ staged, float* __restrict__ Fout)
{
  const int atom = blockIdx.x, tid = threadIdx.x;
  __shared__ float G[2240];
  __shared__ float sdata[8][SSTR];
  __shared__ int opid[CAP];
  __shared__ int pslot[CAP];
  __shared__ int sflb[8];

  int cnt = cursor[atom]; if (cnt > CAP) cnt = CAP;
  if (tid < CAP) opid[tid] = (tid < cnt) ? ord_pid[atom*CAP + tid] : 0x7fffffff;
  __syncthreads();
  if (tid < cnt){                       // rank-sort by pair id -> deterministic
    int my = opid[tid]; int rk = 0;
    for (int j=0;j<cnt;j++) rk += (opid[j] < my);
    pslot[rk] = tid;
  }

  float acc[9];
  int ridx[9], gidx[9], eidx[9];
#pragma unroll
  for (int k=0;k<9;k++){
    acc[k]=0.f;
    int a = tid + (k<<8);
    int ri=0, gi=0, ei=0;
    if (a < 32){ ri = a>>2; gi = 0; ei = a&3; }
    else if (a < 2240){
      int b = a-32; int lb, nl, l, n;
      if (b < 128)      { lb=b;      ei=lb&3; nl=lb>>2; l=nl%4;  n=nl/4;  ri=8 +n; gi=1 +l; }
      else if (b < 448) { lb=b-128;  ei=lb&3; nl=lb>>2; l=nl%10; n=nl/10; ri=16+n; gi=5 +l; }
      else if (b < 1088){ lb=b-448;  ei=lb&3; nl=lb>>2; l=nl%20; n=nl/20; ri=24+n; gi=15+l; }
      else              { lb=b-1088; ei=lb&3; nl=lb>>2; l=nl%35; n=nl/35; ri=32+n; gi=35+l; }
    }
    ridx[k]=ri; gidx[k]=gi; eidx[k]=ei;
  }
  __syncthreads();

  for (int c0=0; c0<cnt; c0+=8){
    const int nc = (cnt-c0 < 8) ? (cnt-c0) : 8;
    if (tid < nc) sflb[tid] = ord_flat[atom*CAP + pslot[c0+tid]];
    __syncthreads();
    for (int idx=tid; idx<nc*SSTR; idx+=256){
      int jj = idx/SSTR, i = idx - jj*SSTR;
      int fsl = sflb[jj];
      sdata[jj][i] = (fsl < SCAP) ? staged[(size_t)fsl*SSTR + i] : 0.f;
    }
    __syncthreads();
    for (int jj=0;jj<nc;jj++){
      const float* sd = sdata[jj];
#pragma unroll
      for (int k=0;k<9;k++)
        acc[k] += sd[ridx[k]] * sd[40+gidx[k]] * sd[110+eidx[k]];
    }
    __syncthreads();
  }

#pragma unroll
  for (int k=0;k<9;k++){
    int a = tid + (k<<8);
    if (a < 2240) G[a] = acc[k];
  }
  __syncthreads();

  float* Fo = Fout + atom*288;
  if (tid < 32) Fo[tid] = G[tid];
  if (tid < 128){
    const int zi = tid>>5, n=(tid>>2)&7, e=tid&3;
    const int L = LTAB[zi], cb = CUMTAB[zi], bs = BASETAB[zi];
    float ap=0.f, am=0.f;
    for (int l=0;l<L;l++){
      float v  = G[bs + ((n*L + l)<<2) + e];
      float v2 = v*v;
      ap += C_ALL [cb+l]*v2;
      am += CS_ALL[cb+l]*v2;
    }
    Fo[32 + (zi<<6)      + (n<<2) + e] = ap;
    Fo[32 + (zi<<6) + 32 + (n<<2) + e] = am;
  }
}

// ---- kernel C: atom MLP (8 atoms/block, split-K) + fused final reduce ------
__global__ __launch_bounds__(512) void k_mlp2(
    const float* __restrict__ F,
    const float* __restrict__ aw1, const float* __restrict__ ab1,
    const float* __restrict__ aw2, const float* __restrict__ ab2,
    const float* __restrict__ aw3, const float* __restrict__ ab3,
    float* __restrict__ partials, int* __restrict__ done,
    float* __restrict__ out)
{
  const int tid = threadIdx.x;
  const int abase = blockIdx.x*8;
  __shared__ float Fs[8][288];
  __shared__ float P1[2][8][256];
  __shared__ float Hs[8][256];
  __shared__ float P2[4][8][128];
  __shared__ float Ps[8][128];
  __shared__ float es[8];
  __shared__ int winner;

  for (int idx=tid; idx<8*288; idx+=512){
    int a = idx/288, i = idx - a*288;
    Fs[a][i] = F[(abase+a)*288 + i];
  }
  __syncthreads();

  // layer 1 (288->256), split-K by 2
  {
    const int o = tid & 255, half = tid >> 8;
    const int i0 = half*144;
    float p1[8];
#pragma unroll
    for (int a=0;a<8;a++) p1[a]=0.f;
    for (int i=i0;i<i0+144;i++){
      float w = aw1[i*256 + o];
#pragma unroll
      for (int a=0;a<8;a++) p1[a] += Fs[a][i]*w;
    }
#pragma unroll
    for (int a=0;a<8;a++) P1[half][a][o] = p1[a];
  }
  __syncthreads();
  {
    const int o = tid & 255, half = tid >> 8;
    if (half == 0){
#pragma unroll
      for (int a=0;a<8;a++)
        Hs[a][o] = silu_f(ab1[o] + P1[0][a][o] + P1[1][a][o]);
    }
  }
  __syncthreads();

  // layer 2 (256->128), split-K by 4
  {
    const int o = tid & 127, q = tid >> 7;
    const int i0 = q*64;
    float p2[8];
#pragma unroll
    for (int a=0;a<8;a++) p2[a]=0.f;
    for (int i=i0;i<i0+64;i++){
      float w = aw2[i*128 + o];
#pragma unroll
      for (int a=0;a<8;a++) p2[a] += Hs[a][i]*w;
    }
#pragma unroll
    for (int a=0;a<8;a++) P2[q][a][o] = p2[a];
  }
  __syncthreads();

  // combine + silu + head weight
#pragma unroll
  for (int rep=0; rep<2; rep++){
    int idx = tid + rep*512;
    int a = idx >> 7, o = idx & 127;
    float h2 = ab2[o] + P2[0][a][o] + P2[1][a][o] + P2[2][a][o] + P2[3][a][o];
    Ps[a][o] = silu_f(h2)*aw3[o];
  }
  __syncthreads();

  // per-atom sums -> block partial
  {
    const int wv = tid >> 6, lane = tid & 63;
    float s = Ps[wv][lane] + Ps[wv][64+lane];
    for (int off=32; off>0; off>>=1) s += __shfl_xor(s, off);
    if (lane == 0) es[wv] = s;
  }
  __syncthreads();
  if (tid == 0){
    float bsum = es[0]+es[1]+es[2]+es[3]+es[4]+es[5]+es[6]+es[7] + 8.0f*ab3[0];
    __hip_atomic_store(&partials[blockIdx.x], bsum,
                       __ATOMIC_RELEASE, __HIP_MEMORY_SCOPE_AGENT);
    int old = __hip_atomic_fetch_add(done, 1, __ATOMIC_ACQ_REL,
                                     __HIP_MEMORY_SCOPE_AGENT);
    winner = (old == (NAT/8) - 1) ? 1 : 0;
  }
  __syncthreads();

  // last block deterministically reduces all 256 partials
  if (winner && tid < 64){
    float s = 0.f;
#pragma unroll
    for (int q=0;q<4;q++)
      s += __hip_atomic_load(&partials[tid*4+q],
                             __ATOMIC_ACQUIRE, __HIP_MEMORY_SCOPE_AGENT);
    for (int off=32; off>0; off>>=1) s += __shfl_xor(s, off);
    if (tid == 0) out[0] = s;
  }
}

extern "C" void kernel_launch(void* const* d_in, const int* in_sizes, int n_in,
                              void* d_out, int out_size, void* d_ws, size_t ws_size,
                              hipStream_t stream) {
  const float* pos  = (const float*)d_in[0];
  const float* cell = (const float*)d_in[1];
  const float* oneh = (const float*)d_in[2];
  const float* sw1  = (const float*)d_in[3];
  const float* sb1  = (const float*)d_in[4];
  const float* sw2  = (const float*)d_in[5];
  const float* sb2  = (const float*)d_in[6];
  const float* rw1  = (const float*)d_in[7];
  const float* rb1  = (const float*)d_in[8];
  const float* rw2  = (const float*)d_in[9];
  const float* rb2  = (const float*)d_in[10];
  const float* aw1  = (const float*)d_in[11];
  const float* ab1  = (const float*)d_in[12];
  const float* aw2  = (const float*)d_in[13];
  const float* ab2  = (const float*)d_in[14];
  const float* aw3  = (const float*)d_in[15];
  const float* ab3  = (const float*)d_in[16];
  const int*   i1   = (const int*)d_in[17];
  const int*   i2   = (const int*)d_in[18];
  const int*   sv   = (const int*)d_in[19];

  char* ws = (char*)d_ws;
  int*   cursor   = (int*)  (ws + 0);         // 8192 B
  int*   nflat    = (int*)  (ws + 8192);      // 4 B
  int*   done     = (int*)  (ws + 8196);      // 4 B   (memset covers 0..8448)
  int*   ord_pid  = (int*)  (ws + 8448);      // NAT*CAP*4 = 524288 B
  int*   ord_flat = (int*)  (ws + 532736);    // 524288 B
  float* staged   = (float*)(ws + 1057024);   // SCAP*SSTR*4 = 3932160 B
  float* F        = (float*)(ws + 4989184);   // NAT*288*4 = 2359296 B
  float* partials = (float*)(ws + 7348480);   // 1024 B -> total ~7.35 MB

  hipMemsetAsync(ws, 0, 8448, stream);        // cursor + nflat + done
  k_pairstage<<<256,  256, 0, stream>>>(pos, cell, oneh, i1, i2, sv,
                                        sw1, sb1, sw2, sb2,
                                        rw1, rb1, rw2, rb2,
                                        cursor, nflat, ord_pid, ord_flat, staged);
  k_feat     <<<NAT,  256, 0, stream>>>(cursor, ord_pid, ord_flat, staged, F);
  k_mlp2     <<<NAT/8,512, 0, stream>>>(F, aw1, ab1, aw2, ab2, aw3, ab3,
                                        partials, done, (float*)d_out);
}

// Round 7
// 67.553 us; speedup vs baseline: 2.7069x; 1.6148x over previous
//
#include <hip/hip_runtime.h>
#include <cmath>

#define NAT  2048
#define NP   65536
#define CAP  64        // per-atom pair bucket capacity
#define SCAP 8192      // compact staged-pair capacity (expected ~3400)
#define SSTR 120       // floats per staged record: rad[40] | g[70] | sp[4] | pad
#define PPB  64        // candidate pairs per block in k_fstage (1024 blocks)

// ---- angular monomial exponent tables --------------------------------------
__constant__ int GLX[70] = {0,
  0,0,0,1,
  0,0,0,0,0,0,1,1,1,2,
  0,0,0,0,0,0,0,0,0,0,1,1,1,1,1,1,2,2,2,3,
  0,0,0,0,0,0,0,0,0,0,0,0,0,0,0,1,1,1,1,1,1,1,1,1,1,2,2,2,2,2,2,3,3,3,4};
__constant__ int GLY[70] = {0,
  0,0,1,0,
  0,0,0,1,1,2,0,0,1,0,
  0,0,0,0,1,1,1,2,2,3,0,0,0,1,1,2,0,0,1,0,
  0,0,0,0,0,1,1,1,1,2,2,2,3,3,4,0,0,0,0,1,1,1,2,2,3,0,0,0,1,1,2,0,0,1,0};
__constant__ int GLZ[70] = {0,
  0,1,0,0,
  0,1,2,0,1,0,0,1,0,0,
  0,1,2,3,0,1,2,0,1,0,0,1,2,0,1,0,0,1,0,0,
  0,1,2,3,4,0,1,2,3,0,1,2,0,1,0,0,1,2,3,0,1,2,0,1,0,0,1,2,0,1,0,0,1,0,0};
// c = z!/((z-n)! lx! ly! lz!), per-zeta blocks
__constant__ float C_ALL[69] = {
  1,1,1,1,
  1,2,1,2,2,1,2,2,2,1,
  1,3,3,1,3,6,3,3,3,1,3,6,3,6,6,3,3,3,3,1,
  1,4,6,4,1,4,12,12,4,6,12,6,4,4,1,4,12,12,4,12,24,12,12,12,4,6,12,6,12,12,6,4,4,4,1};
// c * (-1)^n
__constant__ float CS_ALL[69] = {
  1,-1,-1,-1,
  1,-2,1,-2,2,1,-2,2,2,1,
  1,-3,3,-1,-3,6,-3,3,-3,-1,-3,6,-3,6,-6,-3,3,-3,-3,-1,
  1,-4,6,-4,1,-4,12,-12,4,6,-12,6,-4,4,1,-4,12,-12,4,12,-24,12,-12,12,4,6,-12,6,-12,12,6,-4,4,4,1};
__constant__ int LTAB[4]    = {4,10,20,35};
__constant__ int CUMTAB[4]  = {0,4,14,34};
__constant__ int BASETAB[4] = {32,160,480,1120};

__device__ __forceinline__ float silu_f(float x){ return x / (1.0f + expf(-x)); }

// ---- kernel A: fused filter + LDS-parallel staging -------------------------
// 1024 blocks x 256 thr; block owns PPB=64 candidate pairs. Survivors (~3.3)
// are staged 8-at-a-time by flat work-item decomposition (no shfl chains).
__global__ __launch_bounds__(256) void k_fstage(
    const float* __restrict__ pos, const float* __restrict__ cell,
    const float* __restrict__ oneh,
    const int* __restrict__ i1, const int* __restrict__ i2,
    const int* __restrict__ sv,
    const float* __restrict__ sw1, const float* __restrict__ sb1,
    const float* __restrict__ sw2, const float* __restrict__ sb2,
    const float* __restrict__ rw1, const float* __restrict__ rb1,
    const float* __restrict__ rw2, const float* __restrict__ rb2,
    int* __restrict__ cursor, int* __restrict__ nflat,
    int* __restrict__ ord_pid, int* __restrict__ ord_flat,
    float* __restrict__ staged)
{
  __shared__ float sembt[4][4];
  __shared__ int   spidL[PPB];
  __shared__ int   sfsL[PPB];
  __shared__ int   nsurvS, baseS;
  __shared__ float geo[8][5];      // r, ux, uy, uz, fc
  __shared__ int   gspec[8];
  __shared__ float basis[8][8];
  __shared__ float hbuf[8][64];

  const int tid = threadIdx.x, lane = tid & 63, wid = tid >> 6;

  // per-block species embedding table: wave w computes species w
  {
    float h = silu_f(sb1[lane] + sw1[wid*64 + lane]);
    const float4 w2 = ((const float4*)sw2)[lane];
    float q0=h*w2.x, q1=h*w2.y, q2=h*w2.z, q3=h*w2.w;
#pragma unroll
    for (int off=32; off>0; off>>=1){
      q0 += __shfl_xor(q0, off); q1 += __shfl_xor(q1, off);
      q2 += __shfl_xor(q2, off); q3 += __shfl_xor(q3, off);
    }
    if (lane < 4){
      float v = (lane==0) ? q0+sb2[0] : (lane==1) ? q1+sb2[1]
              : (lane==2) ? q2+sb2[2] : q3+sb2[3];
      sembt[wid][lane] = v;
    }
  }
  if (tid == 0) nsurvS = 0;
  __syncthreads();

  // filter: threads 0..63 test one pair each
  if (tid < PPB){
    const int p = blockIdx.x*PPB + tid;
    const int a = i1[p], b = i2[p];
    const float s0=(float)sv[p*3+0], s1=(float)sv[p*3+1], s2=(float)sv[p*3+2];
    const float rx = pos[b*3+0]-pos[a*3+0] + s0*cell[0]+s1*cell[3]+s2*cell[6];
    const float ry = pos[b*3+1]-pos[a*3+1] + s0*cell[1]+s1*cell[4]+s2*cell[7];
    const float rz = pos[b*3+2]-pos[a*3+2] + s0*cell[2]+s1*cell[5]+s2*cell[8];
    const float r = sqrtf(rx*rx+ry*ry+rz*rz + 1e-12f);
    if (r < 5.0f){
      int ls = atomicAdd(&nsurvS, 1);
      spidL[ls] = p;
    }
  }
  __syncthreads();
  const int ns = nsurvS;
  if (ns == 0) return;
  if (tid == 0) baseS = atomicAdd(nflat, ns);
  __syncthreads();
  const int fbase = baseS;

  // bucket registration (order nondeterministic; k_feat rank-sorts by pid)
  if (tid < ns){
    const int p = spidL[tid];
    const int a = i1[p];
    const int fs = fbase + tid;
    sfsL[tid] = fs;
    int s = atomicAdd(&cursor[a], 1);
    if (s < CAP){ ord_pid[a*CAP+s] = p; ord_flat[a*CAP+s] = fs; }
  }
  __syncthreads();

  // stage survivors 8 at a time, all 256 threads cooperating
  for (int j0=0; j0<ns; j0+=8){
    const int nj = (ns-j0 < 8) ? (ns-j0) : 8;
    if (tid < nj){
      const int p = spidL[j0+tid];
      const int a = i1[p], b = i2[p];
      const float s0=(float)sv[p*3+0], s1=(float)sv[p*3+1], s2=(float)sv[p*3+2];
      const float rx = pos[b*3+0]-pos[a*3+0] + s0*cell[0]+s1*cell[3]+s2*cell[6];
      const float ry = pos[b*3+1]-pos[a*3+1] + s0*cell[1]+s1*cell[4]+s2*cell[7];
      const float rz = pos[b*3+2]-pos[a*3+2] + s0*cell[2]+s1*cell[5]+s2*cell[8];
      const float r  = sqrtf(rx*rx+ry*ry+rz*rz + 1e-12f);
      const float inv= 1.0f/r;
      geo[tid][0]=r; geo[tid][1]=rx*inv; geo[tid][2]=ry*inv; geo[tid][3]=rz*inv;
      geo[tid][4]=0.5f*(cosf(0.6283185307179586f*r)+1.0f);     // pi/RC
      const float o1=oneh[b*4+1], o2=oneh[b*4+2], o3=oneh[b*4+3];
      gspec[tid] = (int)(o1 + 2.0f*o2 + 3.0f*o3 + 0.5f);
    }
    __syncthreads();
    // basis[j][k], nj*8 items
    if (tid < nj*8){
      const int j=tid>>3, k=tid&7;
      const float d = geo[j][0] - (float)k*(5.0f/7.0f);         // linspace(0,5,8)
      basis[j][k] = expf(-d*d*1.28f)*geo[j][4];                 // 1/(2*0.625^2)
    }
    __syncthreads();
    // h[j][o], nj*64 items: 8 FMA each, rw1 coalesced per wave
    for (int idx=tid; idx<nj*64; idx+=256){
      const int j=idx>>6, o=idx&63;
      float h = rb1[o];
#pragma unroll
      for (int k=0;k<8;k++) h += basis[j][k]*rw1[k*64+o];
      hbuf[j][o] = silu_f(h);
    }
    __syncthreads();
    // rad[j][n]: nj*40 items, 64 FMA (hbuf broadcast, rw2 coalesced)
    for (int idx=tid; idx<nj*40; idx+=256){
      const int j=idx/40, n=idx-j*40;
      float racc = rb2[n];
#pragma unroll 8
      for (int o=0;o<64;o++) racc += hbuf[j][o]*rw2[o*40+n];
      const int fs = sfsL[j0+j];
      if (fs < SCAP) staged[(size_t)fs*SSTR + n] = racc*geo[j][4];
    }
    // monomials g[j][l]: nj*70 items
    for (int idx=tid; idx<nj*70; idx+=256){
      const int j=idx/70, l=idx-j*70;
      const float ux=geo[j][1], uy=geo[j][2], uz=geo[j][3];
      const int ex=GLX[l], ey=GLY[l], ez=GLZ[l];
      float g=1.f;
      for (int q=0;q<ex;q++) g*=ux;
      for (int q=0;q<ey;q++) g*=uy;
      for (int q=0;q<ez;q++) g*=uz;
      const int fs = sfsL[j0+j];
      if (fs < SCAP) staged[(size_t)fs*SSTR + 40 + l] = g;
    }
    // species embedding: nj*4 items from per-block table
    if (tid < nj*4){
      const int j=tid>>2, e=tid&3;
      const int fs = sfsL[j0+j];
      if (fs < SCAP) staged[(size_t)fs*SSTR + 110 + e] = sembt[gspec[j]][e];
    }
    __syncthreads();   // protect geo/basis/hbuf reuse
  }
}

// ---- kernel B: per-atom gather-accumulate + feature build ------------------
// Block per atom, 256 threads; thread t owns accumulator slots t+256k, k<9.
__global__ __launch_bounds__(256) void k_feat(
    const int* __restrict__ cursor,
    const int* __restrict__ ord_pid, const int* __restrict__ ord_flat,
    const float* __restrict__ staged, float* __restrict__ Fout)
{
  const int atom = blockIdx.x, tid = threadIdx.x;
  __shared__ float G[2240];
  __shared__ float sdata[8][SSTR];
  __shared__ int opid[CAP];
  __shared__ int pslot[CAP];
  __shared__ int sflb[8];

  int cnt = cursor[atom]; if (cnt > CAP) cnt = CAP;
  if (tid < CAP) opid[tid] = (tid < cnt) ? ord_pid[atom*CAP + tid] : 0x7fffffff;
  __syncthreads();
  if (tid < cnt){                       // rank-sort by pair id -> deterministic
    int my = opid[tid]; int rk = 0;
    for (int j=0;j<cnt;j++) rk += (opid[j] < my);
    pslot[rk] = tid;
  }

  float acc[9];
  int ridx[9], gidx[9], eidx[9];
#pragma unroll
  for (int k=0;k<9;k++){
    acc[k]=0.f;
    int a = tid + (k<<8);
    int ri=0, gi=0, ei=0;
    if (a < 32){ ri = a>>2; gi = 0; ei = a&3; }
    else if (a < 2240){
      int b = a-32; int lb, nl, l, n;
      if (b < 128)      { lb=b;      ei=lb&3; nl=lb>>2; l=nl%4;  n=nl/4;  ri=8 +n; gi=1 +l; }
      else if (b < 448) { lb=b-128;  ei=lb&3; nl=lb>>2; l=nl%10; n=nl/10; ri=16+n; gi=5 +l; }
      else if (b < 1088){ lb=b-448;  ei=lb&3; nl=lb>>2; l=nl%20; n=nl/20; ri=24+n; gi=15+l; }
      else              { lb=b-1088; ei=lb&3; nl=lb>>2; l=nl%35; n=nl/35; ri=32+n; gi=35+l; }
    }
    ridx[k]=ri; gidx[k]=gi; eidx[k]=ei;
  }
  __syncthreads();

  for (int c0=0; c0<cnt; c0+=8){
    const int nc = (cnt-c0 < 8) ? (cnt-c0) : 8;
    if (tid < nc) sflb[tid] = ord_flat[atom*CAP + pslot[c0+tid]];
    __syncthreads();
    for (int idx=tid; idx<nc*SSTR; idx+=256){
      int jj = idx/SSTR, i = idx - jj*SSTR;
      int fsl = sflb[jj];
      sdata[jj][i] = (fsl < SCAP) ? staged[(size_t)fsl*SSTR + i] : 0.f;
    }
    __syncthreads();
    for (int jj=0;jj<nc;jj++){
      const float* sd = sdata[jj];
#pragma unroll
      for (int k=0;k<9;k++)
        acc[k] += sd[ridx[k]] * sd[40+gidx[k]] * sd[110+eidx[k]];
    }
    __syncthreads();
  }

#pragma unroll
  for (int k=0;k<9;k++){
    int a = tid + (k<<8);
    if (a < 2240) G[a] = acc[k];
  }
  __syncthreads();

  float* Fo = Fout + atom*288;
  if (tid < 32) Fo[tid] = G[tid];
  if (tid < 128){
    const int zi = tid>>5, n=(tid>>2)&7, e=tid&3;
    const int L = LTAB[zi], cb = CUMTAB[zi], bs = BASETAB[zi];
    float ap=0.f, am=0.f;
    for (int l=0;l<L;l++){
      float v  = G[bs + ((n*L + l)<<2) + e];
      float v2 = v*v;
      ap += C_ALL [cb+l]*v2;
      am += CS_ALL[cb+l]*v2;
    }
    Fo[32 + (zi<<6)      + (n<<2) + e] = ap;
    Fo[32 + (zi<<6) + 32 + (n<<2) + e] = am;
  }
}

// ---- kernel C: atom MLP (8 atoms/block, split-K) + fused final reduce ------
__global__ __launch_bounds__(512) void k_mlp2(
    const float* __restrict__ F,
    const float* __restrict__ aw1, const float* __restrict__ ab1,
    const float* __restrict__ aw2, const float* __restrict__ ab2,
    const float* __restrict__ aw3, const float* __restrict__ ab3,
    float* __restrict__ partials, int* __restrict__ done,
    float* __restrict__ out)
{
  const int tid = threadIdx.x;
  const int abase = blockIdx.x*8;
  __shared__ float Fs[8][288];
  __shared__ float P1[2][8][256];
  __shared__ float Hs[8][256];
  __shared__ float P2[4][8][128];
  __shared__ float Ps[8][128];
  __shared__ float es[8];
  __shared__ int winner;

  for (int idx=tid; idx<8*288; idx+=512){
    int a = idx/288, i = idx - a*288;
    Fs[a][i] = F[(abase+a)*288 + i];
  }
  __syncthreads();

  // layer 1 (288->256), split-K by 2
  {
    const int o = tid & 255, half = tid >> 8;
    const int i0 = half*144;
    float p1[8];
#pragma unroll
    for (int a=0;a<8;a++) p1[a]=0.f;
    for (int i=i0;i<i0+144;i++){
      float w = aw1[i*256 + o];
#pragma unroll
      for (int a=0;a<8;a++) p1[a] += Fs[a][i]*w;
    }
#pragma unroll
    for (int a=0;a<8;a++) P1[half][a][o] = p1[a];
  }
  __syncthreads();
  {
    const int o = tid & 255, half = tid >> 8;
    if (half == 0){
#pragma unroll
      for (int a=0;a<8;a++)
        Hs[a][o] = silu_f(ab1[o] + P1[0][a][o] + P1[1][a][o]);
    }
  }
  __syncthreads();

  // layer 2 (256->128), split-K by 4
  {
    const int o = tid & 127, q = tid >> 7;
    const int i0 = q*64;
    float p2[8];
#pragma unroll
    for (int a=0;a<8;a++) p2[a]=0.f;
    for (int i=i0;i<i0+64;i++){
      float w = aw2[i*128 + o];
#pragma unroll
      for (int a=0;a<8;a++) p2[a] += Hs[a][i]*w;
    }
#pragma unroll
    for (int a=0;a<8;a++) P2[q][a][o] = p2[a];
  }
  __syncthreads();

  // combine + silu + head weight
#pragma unroll
  for (int rep=0; rep<2; rep++){
    int idx = tid + rep*512;
    int a = idx >> 7, o = idx & 127;
    float h2 = ab2[o] + P2[0][a][o] + P2[1][a][o] + P2[2][a][o] + P2[3][a][o];
    Ps[a][o] = silu_f(h2)*aw3[o];
  }
  __syncthreads();

  // per-atom sums -> block partial
  {
    const int wv = tid >> 6, lane = tid & 63;
    float s = Ps[wv][lane] + Ps[wv][64+lane];
    for (int off=32; off>0; off>>=1) s += __shfl_xor(s, off);
    if (lane == 0) es[wv] = s;
  }
  __syncthreads();
  if (tid == 0){
    float bsum = es[0]+es[1]+es[2]+es[3]+es[4]+es[5]+es[6]+es[7] + 8.0f*ab3[0];
    __hip_atomic_store(&partials[blockIdx.x], bsum,
                       __ATOMIC_RELEASE, __HIP_MEMORY_SCOPE_AGENT);
    int old = __hip_atomic_fetch_add(done, 1, __ATOMIC_ACQ_REL,
                                     __HIP_MEMORY_SCOPE_AGENT);
    winner = (old == (NAT/8) - 1) ? 1 : 0;
  }
  __syncthreads();

  // last block deterministically reduces all 256 partials
  if (winner && tid < 64){
    float s = 0.f;
#pragma unroll
    for (int q=0;q<4;q++)
      s += __hip_atomic_load(&partials[tid*4+q],
                             __ATOMIC_ACQUIRE, __HIP_MEMORY_SCOPE_AGENT);
    for (int off=32; off>0; off>>=1) s += __shfl_xor(s, off);
    if (tid == 0) out[0] = s;
  }
}

extern "C" void kernel_launch(void* const* d_in, const int* in_sizes, int n_in,
                              void* d_out, int out_size, void* d_ws, size_t ws_size,
                              hipStream_t stream) {
  const float* pos  = (const float*)d_in[0];
  const float* cell = (const float*)d_in[1];
  const float* oneh = (const float*)d_in[2];
  const float* sw1  = (const float*)d_in[3];
  const float* sb1  = (const float*)d_in[4];
  const float* sw2  = (const float*)d_in[5];
  const float* sb2  = (const float*)d_in[6];
  const float* rw1  = (const float*)d_in[7];
  const float* rb1  = (const float*)d_in[8];
  const float* rw2  = (const float*)d_in[9];
  const float* rb2  = (const float*)d_in[10];
  const float* aw1  = (const float*)d_in[11];
  const float* ab1  = (const float*)d_in[12];
  const float* aw2  = (const float*)d_in[13];
  const float* ab2  = (const float*)d_in[14];
  const float* aw3  = (const float*)d_in[15];
  const float* ab3  = (const float*)d_in[16];
  const int*   i1   = (const int*)d_in[17];
  const int*   i2   = (const int*)d_in[18];
  const int*   sv   = (const int*)d_in[19];

  char* ws = (char*)d_ws;
  int*   cursor   = (int*)  (ws + 0);         // 8192 B
  int*   nflat    = (int*)  (ws + 8192);      // 4 B
  int*   done     = (int*)  (ws + 8196);      // 4 B   (memset covers 0..8448)
  int*   ord_pid  = (int*)  (ws + 8448);      // NAT*CAP*4 = 524288 B
  int*   ord_flat = (int*)  (ws + 532736);    // 524288 B
  float* staged   = (float*)(ws + 1057024);   // SCAP*SSTR*4 = 3932160 B
  float* F        = (float*)(ws + 4989184);   // NAT*288*4 = 2359296 B
  float* partials = (float*)(ws + 7348480);   // 1024 B -> total ~7.35 MB

  hipMemsetAsync(ws, 0, 8448, stream);        // cursor + nflat + done
  k_fstage<<<NP/PPB, 256, 0, stream>>>(pos, cell, oneh, i1, i2, sv,
                                       sw1, sb1, sw2, sb2,
                                       rw1, rb1, rw2, rb2,
                                       cursor, nflat, ord_pid, ord_flat, staged);
  k_feat  <<<NAT,   256, 0, stream>>>(cursor, ord_pid, ord_flat, staged, F);
  k_mlp2  <<<NAT/8, 512, 0, stream>>>(F, aw1, ab1, aw2, ab2, aw3, ab3,
                                      partials, done, (float*)d_out);
}